// Round 5
// baseline (161.476 us; speedup 1.0000x reference)
//
#include <hip/hip_runtime.h>
#include <math.h>

#define NSPK 1024
#define NUTT 32
#define DIM  128
#define NROWS (NSPK * NUTT)
#define EPS 1e-8f
#define LOG2E 1.44269504f

typedef __attribute__((ext_vector_type(8))) short short8;
typedef __attribute__((ext_vector_type(4))) float floatx4;

__device__ inline unsigned short f2bf(float f) {  // RNE fp32 -> bf16
  union { float f; unsigned u; } v; v.f = f;
  unsigned r = v.u + 0x7fffu + ((v.u >> 16) & 1u);
  return (unsigned short)(r >> 16);
}

// ---------------------------------------------------------------------------
// k1: block b owns speakers {2b, 2b+1} = rows [64b, 64b+64). 512 x 256.
// Writes: centN[spk][d] bf16 unit centroid; per-row rs2/eol/olv (global).
// Block 0 zeroes d_out (k2 atomicAdds into it; dispatch order serializes).
// ---------------------------------------------------------------------------
__global__ __launch_bounds__(256) void k1(const float* __restrict__ emb,
                                          const float* __restrict__ wp,
                                          const float* __restrict__ bp,
                                          unsigned short* __restrict__ centN,
                                          float* __restrict__ rs2g,
                                          float* __restrict__ eolg,
                                          float* __restrict__ olvg,
                                          float* __restrict__ out) {
  __shared__ __align__(16) float Sl[2 * 128];
  __shared__ float red[4];

  int b = blockIdx.x, t = threadIdx.x;
  float w = wp[0], bb = bp[0];
  float M = bb + fabsf(w);
  if (b == 0 && t == 0) out[0] = 0.f;

  int sp = t >> 7, d = t & 127;
  {
    const float* eb = emb + (size_t)(b * 2 + sp) * NUTT * DIM + d;
    float s = 0.f;
#pragma unroll
    for (int m = 0; m < NUTT; ++m) s += eb[m * DIM];
    Sl[sp * 128 + d] = s;
    float p = s * s;
#pragma unroll
    for (int mask = 1; mask < 64; mask <<= 1) p += __shfl_xor(p, mask, 64);
    if ((t & 63) == 0) red[t >> 6] = p;
  }
  __syncthreads();
  float ss0 = red[0] + red[1], ss1 = red[2] + red[3];

  {  // normalized bf16 centroid
    float ss = sp ? ss1 : ss0;
    float s = Sl[sp * 128 + d];
    float cn = fmaxf(sqrtf(ss) * (1.0f / NUTT), EPS);
    centN[(size_t)(b * 2 + sp) * DIM + d] = f2bf(s / (NUTT * cn));
  }

  {  // per-row stats: 4 threads/row, 32 dims each (L1-hot re-read of emb)
    int row = t >> 2, sub = t & 3;
    int rsp = row >> 5;
    const float* er = emb + (size_t)(b * 64 + row) * DIM + sub * 32;
    const float* Srow = &Sl[rsp * 128 + sub * 32];
    float ee = 0.f, es = 0.f;
#pragma unroll
    for (int i = 0; i < 8; ++i) {
      float4 ev = *(const float4*)&er[i * 4];
      float4 sv = *(const float4*)&Srow[i * 4];
      ee += ev.x * ev.x + ev.y * ev.y + ev.z * ev.z + ev.w * ev.w;
      es += ev.x * sv.x + ev.y * sv.y + ev.z * sv.z + ev.w * sv.w;
    }
    ee += __shfl_xor(ee, 1, 64); es += __shfl_xor(es, 1, 64);
    ee += __shfl_xor(ee, 2, 64); es += __shfl_xor(es, 2, 64);
    if (sub == 0) {
      float ss = rsp ? ss1 : ss0;
      float en = fmaxf(sqrtf(ee), EPS);
      float dot_own = (es - ee) * (1.0f / (NUTT - 1));
      float ex2 = (ss - 2.f * es + ee) * (1.0f / ((NUTT - 1) * (NUTT - 1)));
      float cen = fmaxf(sqrtf(ex2), EPS);
      float ol = w * dot_own / (en * cen) + bb;
      int gr = b * 64 + row;
      olvg[gr] = ol;
      eolg[gr] = exp2f((ol - M) * LOG2E);
      rs2g[gr] = w * LOG2E / en;
    }
  }
}

// ---------------------------------------------------------------------------
// k2: 512 blocks x 512 threads (8 waves). Block = 64 rows x 1024 cols.
// Wave w: rows half h=w>>2 (32 rows), cols quarter q=w&3 (256 cols, 16 tiles).
// VGPR budget ~120 (<128) -> 4 waves/SIMD, 16 waves/CU: latency-hiding TLP.
// Fixed-max LSE: sAcc += exp2(fma(rs2, acc, c2)); own col (= 2b+h, wave-
// uniform) patched with exact fp32 exclusive-centroid value.
// ---------------------------------------------------------------------------
__global__ __launch_bounds__(512, 4) void k2(const float* __restrict__ emb,
                                             const unsigned short* __restrict__ centN,
                                             const float* __restrict__ rs2g,
                                             const float* __restrict__ eolg,
                                             const float* __restrict__ olvg,
                                             const float* __restrict__ wp,
                                             const float* __restrict__ bp,
                                             float* __restrict__ out) {
  __shared__ __align__(16) unsigned short A[64 * 136];  // bf16, pad 136
  __shared__ __align__(16) float sPart[256];            // [wave][32 rows]

  int b = blockIdx.x, t = threadIdx.x;
  float w = wp[0], bb = bp[0];
  float M = bb + fabsf(w);
  float c2 = -fabsf(w) * LOG2E;

  // stage A: 64x128 fp32 -> bf16 LDS (coalesced float4)
#pragma unroll
  for (int i = 0; i < 4; ++i) {
    int idx4 = t + 512 * i;
    int r = idx4 >> 5, d4 = (idx4 & 31) << 2;
    float4 v = *(const float4*)(emb + (size_t)b * 8192 + (size_t)idx4 * 4);
    ushort4 bv;
    bv.x = f2bf(v.x); bv.y = f2bf(v.y); bv.z = f2bf(v.z); bv.w = f2bf(v.w);
    *(ushort4*)&A[r * 136 + d4] = bv;
  }
  __syncthreads();

  int wid = t >> 6, lane = t & 63, lg = lane >> 4, lc = lane & 15;
  int h = wid >> 2, q = wid & 3;
  int own = b * 2 + h;  // wave-uniform own-speaker column

  short8 af[2][4];  // rows h*32 + rt*16 + lc, k = ks*32 + lg*8
#pragma unroll
  for (int rt = 0; rt < 2; ++rt)
#pragma unroll
    for (int ks = 0; ks < 4; ++ks)
      af[rt][ks] = *(const short8*)&A[(h * 32 + rt * 16 + lc) * 136 + ks * 32 + lg * 8];

  float rsL[8], eolL[8];  // rows h*32 + rt*16 + lg*4 + reg
#pragma unroll
  for (int rt = 0; rt < 2; ++rt) {
    float4 r4 = *(const float4*)&rs2g[b * 64 + h * 32 + rt * 16 + lg * 4];
    float4 o4 = *(const float4*)&eolg[b * 64 + h * 32 + rt * 16 + lg * 4];
    rsL[rt * 4 + 0] = r4.x; rsL[rt * 4 + 1] = r4.y; rsL[rt * 4 + 2] = r4.z; rsL[rt * 4 + 3] = r4.w;
    eolL[rt * 4 + 0] = o4.x; eolL[rt * 4 + 1] = o4.y; eolL[rt * 4 + 2] = o4.z; eolL[rt * 4 + 3] = o4.w;
  }

  float sAcc[8];
#pragma unroll
  for (int j = 0; j < 8; ++j) sAcc[j] = 0.f;

  int colbase = q * 256;
  int col0 = colbase + lc;
  const short8* cb8 = (const short8*)centN;  // col c -> 16 short8s

  short8 bcur[4], bnxt[4];
  {
    const short8* p = cb8 + (size_t)col0 * 16 + lg;
    bcur[0] = p[0]; bcur[1] = p[4]; bcur[2] = p[8]; bcur[3] = p[12];
  }

  for (int ct = 0; ct < 16; ++ct) {
    if (ct < 15) {  // prefetch next tile's B frags
      const short8* p = cb8 + (size_t)(col0 + (ct + 1) * 16) * 16 + lg;
      bnxt[0] = p[0]; bnxt[1] = p[4]; bnxt[2] = p[8]; bnxt[3] = p[12];
    }
    floatx4 acc[2];
#pragma unroll
    for (int rt = 0; rt < 2; ++rt) acc[rt] = (floatx4){0.f, 0.f, 0.f, 0.f};
#pragma unroll
    for (int ks = 0; ks < 4; ++ks)
#pragma unroll
      for (int rt = 0; rt < 2; ++rt)
        acc[rt] = __builtin_amdgcn_mfma_f32_16x16x32_bf16(af[rt][ks], bcur[ks], acc[rt], 0, 0, 0);

    int c0 = colbase + ct * 16, col = c0 + lc;
    bool fix = (unsigned)(own - c0) < 16u;  // uniform branch per tile
#pragma unroll
    for (int rt = 0; rt < 2; ++rt)
#pragma unroll
      for (int reg = 0; reg < 4; ++reg) {
        float l2 = fmaf(rsL[rt * 4 + reg], acc[rt][reg], c2);
        float e = exp2f(l2);
        if (fix && col == own) e = eolL[rt * 4 + reg];
        sAcc[rt * 4 + reg] += e;
      }
#pragma unroll
    for (int ks = 0; ks < 4; ++ks) bcur[ks] = bnxt[ks];
  }

  // reduce over the 16 col-lanes (lc), lanes lg*16+lc
#pragma unroll
  for (int mask = 1; mask < 16; mask <<= 1)
#pragma unroll
    for (int j = 0; j < 8; ++j) sAcc[j] += __shfl_xor(sAcc[j], mask, 64);

  if (lc == 0)
#pragma unroll
    for (int rt = 0; rt < 2; ++rt)
#pragma unroll
      for (int reg = 0; reg < 4; ++reg)
        sPart[wid * 32 + rt * 16 + lg * 4 + reg] = sAcc[rt * 4 + reg];
  __syncthreads();

  if (t < 64) {
    int hh = t >> 5, ri = t & 31;
    float st = sPart[(hh * 4 + 0) * 32 + ri] + sPart[(hh * 4 + 1) * 32 + ri] +
               sPart[(hh * 4 + 2) * 32 + ri] + sPart[(hh * 4 + 3) * 32 + ri];
    float lossr = M + logf(st) - olvg[b * 64 + t];
#pragma unroll
    for (int mask = 1; mask < 64; mask <<= 1) lossr += __shfl_xor(lossr, mask, 64);
    if (t == 0) atomicAdd(out, lossr * (1.0f / NROWS));
  }
}

// ---------------------------------------------------------------------------
extern "C" void kernel_launch(void* const* d_in, const int* in_sizes, int n_in,
                              void* d_out, int out_size, void* d_ws, size_t ws_size,
                              hipStream_t stream) {
  const float* emb = (const float*)d_in[0];
  const float* wp  = (const float*)d_in[1];
  const float* bp  = (const float*)d_in[2];

  char* ws = (char*)d_ws;
  unsigned short* centN = (unsigned short*)ws;          // 256 KB
  float* rs2g = (float*)(ws + 262144);                  // 128 KB
  float* eolg = (float*)(ws + 262144 + 131072);         // 128 KB
  float* olvg = (float*)(ws + 262144 + 262144);         // 128 KB
  float* out = (float*)d_out;

  hipLaunchKernelGGL(k1, dim3(512), dim3(256), 0, stream,
                     emb, wp, bp, centN, rs2g, eolg, olvg, out);
  hipLaunchKernelGGL(k2, dim3(512), dim3(512), 0, stream,
                     emb, centN, rs2g, eolg, olvg, wp, bp, out);
}

// Round 6
// 93.805 us; speedup vs baseline: 1.7214x; 1.7214x over previous
//
#include <hip/hip_runtime.h>
#include <math.h>

#define NSPK 1024
#define NUTT 32
#define DIM  128
#define NROWS (NSPK * NUTT)
#define EPS 1e-8f
#define LOG2E 1.44269504f

typedef __attribute__((ext_vector_type(8))) short short8;
typedef __attribute__((ext_vector_type(4))) float floatx4;

__device__ inline unsigned short f2bf(float f) {  // RNE fp32 -> bf16
  union { float f; unsigned u; } v; v.f = f;
  unsigned r = v.u + 0x7fffu + ((v.u >> 16) & 1u);
  return (unsigned short)(r >> 16);
}

// ---------------------------------------------------------------------------
// k1: block b owns speakers {2b, 2b+1} = rows [64b, 64b+64). 512 x 256.
// Writes: centN[spk][d] bf16 unit centroid; per-row rs2/eol/olv (global).
// Block 0 zeroes d_out (k2 atomicAdds into it; dispatch order serializes).
// ---------------------------------------------------------------------------
__global__ __launch_bounds__(256) void k1(const float* __restrict__ emb,
                                          const float* __restrict__ wp,
                                          const float* __restrict__ bp,
                                          unsigned short* __restrict__ centN,
                                          float* __restrict__ rs2g,
                                          float* __restrict__ eolg,
                                          float* __restrict__ olvg,
                                          float* __restrict__ out) {
  __shared__ __align__(16) float Sl[2 * 128];
  __shared__ float red[4];

  int b = blockIdx.x, t = threadIdx.x;
  float w = wp[0], bb = bp[0];
  float M = bb + fabsf(w);
  if (b == 0 && t == 0) out[0] = 0.f;

  int sp = t >> 7, d = t & 127;
  {
    const float* eb = emb + (size_t)(b * 2 + sp) * NUTT * DIM + d;
    float s = 0.f;
#pragma unroll
    for (int m = 0; m < NUTT; ++m) s += eb[m * DIM];
    Sl[sp * 128 + d] = s;
    float p = s * s;
#pragma unroll
    for (int mask = 1; mask < 64; mask <<= 1) p += __shfl_xor(p, mask, 64);
    if ((t & 63) == 0) red[t >> 6] = p;
  }
  __syncthreads();
  float ss0 = red[0] + red[1], ss1 = red[2] + red[3];

  {  // normalized bf16 centroid
    float ss = sp ? ss1 : ss0;
    float s = Sl[sp * 128 + d];
    float cn = fmaxf(sqrtf(ss) * (1.0f / NUTT), EPS);
    centN[(size_t)(b * 2 + sp) * DIM + d] = f2bf(s / (NUTT * cn));
  }

  {  // per-row stats: 4 threads/row, 32 dims each (L1-hot re-read of emb)
    int row = t >> 2, sub = t & 3;
    int rsp = row >> 5;
    const float* er = emb + (size_t)(b * 64 + row) * DIM + sub * 32;
    const float* Srow = &Sl[rsp * 128 + sub * 32];
    float ee = 0.f, es = 0.f;
#pragma unroll
    for (int i = 0; i < 8; ++i) {
      float4 ev = *(const float4*)&er[i * 4];
      float4 sv = *(const float4*)&Srow[i * 4];
      ee += ev.x * ev.x + ev.y * ev.y + ev.z * ev.z + ev.w * ev.w;
      es += ev.x * sv.x + ev.y * sv.y + ev.z * sv.z + ev.w * sv.w;
    }
    ee += __shfl_xor(ee, 1, 64); es += __shfl_xor(es, 1, 64);
    ee += __shfl_xor(ee, 2, 64); es += __shfl_xor(es, 2, 64);
    if (sub == 0) {
      float ss = rsp ? ss1 : ss0;
      float en = fmaxf(sqrtf(ee), EPS);
      float dot_own = (es - ee) * (1.0f / (NUTT - 1));
      float ex2 = (ss - 2.f * es + ee) * (1.0f / ((NUTT - 1) * (NUTT - 1)));
      float cen = fmaxf(sqrtf(ex2), EPS);
      float ol = w * dot_own / (en * cen) + bb;
      int gr = b * 64 + row;
      olvg[gr] = ol;
      eolg[gr] = exp2f((ol - M) * LOG2E);
      rs2g[gr] = w * LOG2E / en;
    }
  }
}

// ---------------------------------------------------------------------------
// k2: 512 blocks x 256 threads (4 waves), 2 blocks/CU. Block = 64 rows x
// 1024 cols. B staged cooperatively to LDS (16 passes x 64 cols, coalesced
// dwordx4, double-buffered register relay) -- round-1's proven low-FETCH
// pattern. Wave w computes its 16-col sub-tile x 64 rows per pass.
// A-frags in regs; fixed-max exp2 LSE epilogue.
// ---------------------------------------------------------------------------
__global__ __launch_bounds__(256, 2) void k2(const float* __restrict__ emb,
                                             const unsigned short* __restrict__ centN,
                                             const float* __restrict__ rs2g,
                                             const float* __restrict__ eolg,
                                             const float* __restrict__ olvg,
                                             const float* __restrict__ wp,
                                             const float* __restrict__ bp,
                                             float* __restrict__ out) {
  __shared__ __align__(16) unsigned short A[64 * 136];      // 17.4 KB
  __shared__ __align__(16) unsigned short Bb[2][64 * 136];  // 34.8 KB
  __shared__ __align__(16) float sPart[256];

  int b = blockIdx.x, t = threadIdx.x;
  float w = wp[0], bb = bp[0];
  float M = bb + fabsf(w);
  float c2 = -fabsf(w) * LOG2E;

  // stage A: 64x128 fp32 -> bf16 LDS (coalesced float4)
#pragma unroll
  for (int i = 0; i < 8; ++i) {
    int idx4 = t + 256 * i;
    int r = idx4 >> 5, d4 = (idx4 & 31) << 2;
    float4 v = *(const float4*)(emb + (size_t)b * 8192 + (size_t)idx4 * 4);
    ushort4 bv;
    bv.x = f2bf(v.x); bv.y = f2bf(v.y); bv.z = f2bf(v.z); bv.w = f2bf(v.w);
    *(ushort4*)&A[r * 136 + d4] = bv;
  }
  __syncthreads();

  int wid = t >> 6, lane = t & 63, lg = lane >> 4, lc = lane & 15;

  short8 af[4][4];  // rows rt*16+lc, k = ks*32 + lg*8
#pragma unroll
  for (int rt = 0; rt < 4; ++rt)
#pragma unroll
    for (int ks = 0; ks < 4; ++ks)
      af[rt][ks] = *(const short8*)&A[(rt * 16 + lc) * 136 + ks * 32 + lg * 8];

  float rsL[16], eolL[16];  // rows rt*16 + lg*4 + reg
#pragma unroll
  for (int rt = 0; rt < 4; ++rt) {
    float4 r4 = *(const float4*)&rs2g[b * 64 + rt * 16 + lg * 4];
    float4 o4 = *(const float4*)&eolg[b * 64 + rt * 16 + lg * 4];
    rsL[rt * 4 + 0] = r4.x; rsL[rt * 4 + 1] = r4.y; rsL[rt * 4 + 2] = r4.z; rsL[rt * 4 + 3] = r4.w;
    eolL[rt * 4 + 0] = o4.x; eolL[rt * 4 + 1] = o4.y; eolL[rt * 4 + 2] = o4.z; eolL[rt * 4 + 3] = o4.w;
  }

  float sAcc[16];
#pragma unroll
  for (int j = 0; j < 16; ++j) sAcc[j] = 0.f;

  // Register relay for B staging: thread t carries 4 x 16B chunks per pass.
  // Chunk f = t + 256*i (f in [0,1024)): col = f>>4 (64 cols), kq = f&15
  // (16B sub-chunk). Global source is fully contiguous per wave (4 KB).
  short8 R[4];
#pragma unroll
  for (int i = 0; i < 4; ++i) {
    int f = t + 256 * i;
    R[i] = *(const short8*)(centN + (size_t)(f >> 4) * DIM + (f & 15) * 8);
  }

  for (int p = 0; p < 16; ++p) {
    unsigned short* Bp = Bb[p & 1];
    __syncthreads();  // buffer free (consumers of pass p-2 done)
#pragma unroll
    for (int i = 0; i < 4; ++i) {
      int f = t + 256 * i;
      *(short8*)&Bp[(f >> 4) * 136 + (f & 15) * 8] = R[i];
    }
    {  // prefetch next pass while computing this one (wraps to 0 at end)
      int pn = (p + 1) & 15;
#pragma unroll
      for (int i = 0; i < 4; ++i) {
        int f = t + 256 * i;
        R[i] = *(const short8*)(centN + (size_t)(pn * 64 + (f >> 4)) * DIM + (f & 15) * 8);
      }
    }
    __syncthreads();  // buffer ready

    // wave wid consumes cols [p*64 + wid*16, +16)
    short8 bf[4];
#pragma unroll
    for (int ks = 0; ks < 4; ++ks)
      bf[ks] = *(const short8*)&Bp[(wid * 16 + lc) * 136 + ks * 32 + lg * 8];

    floatx4 acc[4];
#pragma unroll
    for (int rt = 0; rt < 4; ++rt) acc[rt] = (floatx4){0.f, 0.f, 0.f, 0.f};
#pragma unroll
    for (int ks = 0; ks < 4; ++ks)
#pragma unroll
      for (int rt = 0; rt < 4; ++rt)
        acc[rt] = __builtin_amdgcn_mfma_f32_16x16x32_bf16(af[rt][ks], bf[ks], acc[rt], 0, 0, 0);

    int col = p * 64 + wid * 16 + lc;
#pragma unroll
    for (int rt = 0; rt < 4; ++rt) {
      int own = b * 2 + (rt >> 1);
      bool isown = (col == own);
#pragma unroll
      for (int reg = 0; reg < 4; ++reg) {
        float l2 = fmaf(rsL[rt * 4 + reg], acc[rt][reg], c2);
        float e = exp2f(l2);
        if (isown) e = eolL[rt * 4 + reg];
        sAcc[rt * 4 + reg] += e;
      }
    }
  }

  // reduce over the 16 col-lanes (lc)
#pragma unroll
  for (int mask = 1; mask < 16; mask <<= 1)
#pragma unroll
    for (int j = 0; j < 16; ++j) sAcc[j] += __shfl_xor(sAcc[j], mask, 64);

  if (lc == 0)
#pragma unroll
    for (int rt = 0; rt < 4; ++rt)
#pragma unroll
      for (int reg = 0; reg < 4; ++reg)
        sPart[wid * 64 + rt * 16 + lg * 4 + reg] = sAcc[rt * 4 + reg];
  __syncthreads();

  if (t < 64) {
    float st = sPart[t] + sPart[64 + t] + sPart[128 + t] + sPart[192 + t];
    float lossr = M + logf(st) - olvg[b * 64 + t];
#pragma unroll
    for (int mask = 1; mask < 64; mask <<= 1) lossr += __shfl_xor(lossr, mask, 64);
    if (t == 0) atomicAdd(out, lossr * (1.0f / NROWS));
  }
}

// ---------------------------------------------------------------------------
extern "C" void kernel_launch(void* const* d_in, const int* in_sizes, int n_in,
                              void* d_out, int out_size, void* d_ws, size_t ws_size,
                              hipStream_t stream) {
  const float* emb = (const float*)d_in[0];
  const float* wp  = (const float*)d_in[1];
  const float* bp  = (const float*)d_in[2];

  char* ws = (char*)d_ws;
  unsigned short* centN = (unsigned short*)ws;          // 256 KB
  float* rs2g = (float*)(ws + 262144);                  // 128 KB
  float* eolg = (float*)(ws + 262144 + 131072);         // 128 KB
  float* olvg = (float*)(ws + 262144 + 262144);         // 128 KB
  float* out = (float*)d_out;

  hipLaunchKernelGGL(k1, dim3(512), dim3(256), 0, stream,
                     emb, wp, bp, centN, rs2g, eolg, olvg, out);
  hipLaunchKernelGGL(k2, dim3(512), dim3(256), 0, stream,
                     emb, centN, rs2g, eolg, olvg, wp, bp, out);
}